// Round 1
// 2799.924 us; speedup vs baseline: 7.7997x; 7.7997x over previous
//
#include <hip/hip_runtime.h>

#define B_ 256
#define T_ 500
#define I_ 8
#define H_ 1024
#define O_ 8
#define NSTEP (T_ - 1)
#define EXC_N 819   // int(0.8 * 1024)

typedef unsigned short u16;
typedef __attribute__((ext_vector_type(8))) short short8;
typedef __attribute__((ext_vector_type(4))) float f32x4;

// r-exchange ping-pong + per-group barrier counters in module globals
// (d_ws size unknown; module .bss is safe and not harness-poisoned).
__device__ __attribute__((aligned(16))) u16 g_rbuf[2 * B_ * H_];
__device__ unsigned int g_cnt[16 * 32];

__device__ __forceinline__ float bf2f(u16 u) {
    union { unsigned int i; float f; } v;
    v.i = ((unsigned int)u) << 16;
    return v.f;
}
__device__ __forceinline__ u16 f2bf(float f) {
    union { float f; unsigned int i; } v;
    v.f = f;
    unsigned int u = v.i;
    return (u16)((u + 0x7fffu + ((u >> 16) & 1u)) >> 16);
}
__device__ __forceinline__ float sp_(float v) {   // softplus, beta=1
    float e = __expf(-fabsf(v));
    return fmaxf(v, 0.0f) + __logf(1.0f + e);
}

__global__ void rnn_init() {
    g_cnt[threadIdx.x] = 0u;
    g_cnt[threadIdx.x + 256] = 0u;
}

// INPUTS ARE FP32 (reference dtypes). Internally: effWg + r in bf16 for MFMA,
// h state fp32 in registers, output fp32.
// Grid: 256 WGs = 16 batch-groups (grp = bid&15, 16 rows each) x 16 j-slices
// (ntw = bid>>4, 64 hidden units each). effWg slice lives in VGPRs as MFMA
// B-frags for all 499 steps; r exchanged via ping-pong global buffer.
//
// SYNC SCHEME (this revision): NO __threadfence / release-RMW — those lower to
// buffer_wbl2/buffer_inv (full per-XCD L2 writeback+invalidate) on gfx950 and
// were ~40 us/step of pure stall. Instead, all cross-WG communicated data
// (r buffer, counters) uses RELAXED agent-scope atomics (sc1-flagged accesses,
// coherent at the device coherence point, no cache maintenance). Release edge
// is built manually: sc1 r-stores -> s_waitcnt vmcnt(0) (per wave) ->
// __syncthreads -> relaxed fetch_add. Acquire edge: spin on relaxed load ->
// __syncthreads -> r-loads as relaxed agent u64 atomic loads (bypass stale
// L1/L2). Ping-pong reuse safety is unchanged: a buffer is only overwritten
// after all 16 WGs signaled the step in which it was last consumed.
__global__ void __launch_bounds__(256, 1)
rnn_persist(const float* __restrict__ x, const float* __restrict__ noise,
            const float* __restrict__ wi, const float* __restrict__ wrec,
            const float* __restrict__ wout, const float* __restrict__ bb,
            const float* __restrict__ gg, const float* __restrict__ h0,
            const float* __restrict__ mwrec, float* __restrict__ out)
{
    const int bid = blockIdx.x;
    const int grp = bid & 15;        // batch group (16 rows)
    const int ntw = bid >> 4;        // j-slice 0..15
    const int jb  = ntw * 64;
    const int tid = threadIdx.x;
    const int w   = tid >> 6;        // wave = K-slice of 256
    const int l   = tid & 63;
    const int lm  = l & 15;
    const int lk  = l >> 4;
    const int kb  = w * 256;
    const int je  = jb + l;          // epilogue thread's j

    __shared__ float part[4 * 16 * 68];   // [wave][m][jj pad 68] fp32 partials
    __shared__ float xbuf[16 * 8];
    __shared__ float outred[64];

    // ---- per-thread constants ----
    float wiv[8];
#pragma unroll
    for (int i = 0; i < 8; ++i) wiv[i] = wi[i * H_ + je];
    const float bTe = bb[je];
    float h[4];
    {
        float h0j = h0[je];
        h[0] = h[1] = h[2] = h[3] = h0j;
    }

    // ---- B fragments: effWg[k][j] = relu(wrec[j,k]*ei[k])*ei[k]*mwrec[j,k]*relu(g[k]) ----
    // B layout (16x16x32): col = lane&15, k = kf*32 + 8*(lane>>4) + i
    short8 Bf[8][4];
#pragma unroll
    for (int kf = 0; kf < 8; ++kf) {
#pragma unroll
        for (int n4 = 0; n4 < 4; ++n4) {
            const int jB = jb + n4 * 16 + lm;
            const int k0 = kb + kf * 32 + 8 * lk;
            short8 r;
#pragma unroll
            for (int i = 0; i < 8; ++i) {
                const int k = k0 + i;
                const float ei = (k < EXC_N) ? 1.0f : -1.0f;
                const float wf = wrec[jB * H_ + k];
                const float mf = mwrec[jB * H_ + k];
                const float gf = fmaxf(gg[k], 0.0f);
                const float e  = fmaxf(wf * ei, 0.0f) * ei * mf * gf;
                r[i] = (short)f2bf(e);
            }
            Bf[kf][n4] = r;
        }
    }

    // ---- wout column slice (only WGs ntw<8 produce output column ntw) ----
    float wo[64];
    if (ntw < O_) {
#pragma unroll
        for (int kf = 0; kf < 8; ++kf)
#pragma unroll
            for (int i = 0; i < 8; ++i) {
                const int k = kb + kf * 32 + 8 * lk + i;
                wo[kf * 8 + i] = wout[k * O_ + ntw];
            }
    }

    // ---- A fragments for t=0: r0[k] = softplus(h0[k]+b[k]), same for all rows ----
    short8 Af[8];
#pragma unroll
    for (int kf = 0; kf < 8; ++kf) {
        const int k0 = kb + kf * 32 + 8 * lk;
        short8 a;
#pragma unroll
        for (int i = 0; i < 8; ++i)
            a[i] = (short)f2bf(sp_(h0[k0 + i] + bb[k0 + i]));
        Af[kf] = a;
    }

    // ---- prefetch noise(0), x(0) ----
    float nprev[4];
#pragma unroll
    for (int q = 0; q < 4; ++q)
        nprev[q] = noise[(grp * 16 + w * 4 + q) * (T_ * H_) + je];
    float xp = 0.0f;
    if (tid < 128) xp = x[(grp * 16 + (tid >> 3)) * (T_ * I_) + (tid & 7)];

    unsigned int* myc = g_cnt + grp * 32;   // 128B-spaced per-group counter

    for (int t = 0; t < NSTEP; ++t) {
        // stage x_t
        if (tid < 128) xbuf[tid] = xp;

        // MFMA: partial D = r_t @ effWg^T over this wave's K slice
        f32x4 acc0 = {0,0,0,0}, acc1 = {0,0,0,0}, acc2 = {0,0,0,0}, acc3 = {0,0,0,0};
#pragma unroll
        for (int kf = 0; kf < 8; ++kf) {
            acc0 = __builtin_amdgcn_mfma_f32_16x16x32_bf16(Af[kf], Bf[kf][0], acc0, 0, 0, 0);
            acc1 = __builtin_amdgcn_mfma_f32_16x16x32_bf16(Af[kf], Bf[kf][1], acc1, 0, 0, 0);
            acc2 = __builtin_amdgcn_mfma_f32_16x16x32_bf16(Af[kf], Bf[kf][2], acc2, 0, 0, 0);
            acc3 = __builtin_amdgcn_mfma_f32_16x16x32_bf16(Af[kf], Bf[kf][3], acc3, 0, 0, 0);
        }
        // D layout: m = 4*lk + reg, jj = n4*16 + lm
#pragma unroll
        for (int reg = 0; reg < 4; ++reg) {
            const int m = 4 * lk + reg;
            part[(w * 16 + m) * 68 +  0 + lm] = acc0[reg];
            part[(w * 16 + m) * 68 + 16 + lm] = acc1[reg];
            part[(w * 16 + m) * 68 + 32 + lm] = acc2[reg];
            part[(w * 16 + m) * 68 + 48 + lm] = acc3[reg];
        }
        __syncthreads();

        // h update (fp32 state in regs), produce r_{t+1} (bf16)
        u16 rsto[4];
#pragma unroll
        for (int q = 0; q < 4; ++q) {
            const int m = w * 4 + q;
            float D = part[(0 * 16 + m) * 68 + l] + part[(1 * 16 + m) * 68 + l]
                    + part[(2 * 16 + m) * 68 + l] + part[(3 * 16 + m) * 68 + l];
            float inp = 0.0f;
#pragma unroll
            for (int i = 0; i < 8; ++i) inp = fmaf(xbuf[m * 8 + i], wiv[i], inp);
            float hn = h[q] + 0.05f * nprev[q] + 0.2f * (-h[q] + D + inp);
            hn = fminf(fmaxf(hn, -64.0f), 64.0f);   // inert if dynamics correct (|h|<~20)
            h[q] = hn;
            rsto[q] = f2bf(sp_(hn + bTe));
        }
        // r store: pair-pack adjacent lanes' bf16 into u32, store write-through
        // (relaxed agent atomic -> sc1, coherent at device coherence point,
        //  no cache-maintenance ops)
        {
            unsigned int* rb32 = (unsigned int*)(g_rbuf + ((t + 1) & 1) * (B_ * H_)
                                                 + (grp * 16) * H_);
#pragma unroll
            for (int q = 0; q < 4; ++q) {
                unsigned int mine = (unsigned int)rsto[q];
                unsigned int nb   = (unsigned int)__shfl_xor((int)mine, 1, 64);
                if ((l & 1) == 0) {
                    unsigned int packed = (mine & 0xffffu) | (nb << 16);
                    __hip_atomic_store(rb32 + (((w * 4 + q) * H_ + je) >> 1), packed,
                                       __ATOMIC_RELAXED, __HIP_MEMORY_SCOPE_AGENT);
                }
            }
        }

        // release edge (manual): drain this wave's coherent stores, barrier so
        // all 4 waves' stores are complete, then relaxed signal. NO wbl2/inv.
        asm volatile("s_waitcnt vmcnt(0)" ::: "memory");
        __syncthreads();
        if (tid == 0)
            __hip_atomic_fetch_add(myc, 1u, __ATOMIC_RELAXED, __HIP_MEMORY_SCOPE_AGENT);

        // prefetch next-step streams AFTER the signal (keeps HBM latency off the signal path)
#pragma unroll
        for (int q = 0; q < 4; ++q)
            nprev[q] = noise[(grp * 16 + w * 4 + q) * (T_ * H_) + (t + 1) * H_ + je];
        if (tid < 128 && t + 1 < NSTEP)
            xp = x[(grp * 16 + (tid >> 3)) * (T_ * I_) + (t + 1) * I_ + (tid & 7)];

        // deferred output row t from r_t (still in Af) — hides in the spin window
        if (ntw < O_) {
            float po = 0.0f;
#pragma unroll
            for (int kf = 0; kf < 8; ++kf) {
                const short8 a = Af[kf];
#pragma unroll
                for (int i = 0; i < 8; ++i)
                    po = fmaf(bf2f((u16)a[i]), wo[kf * 8 + i], po);
            }
            po += __shfl_xor(po, 16, 64);
            po += __shfl_xor(po, 32, 64);
            if (l < 16) outred[w * 16 + l] = po;
            __syncthreads();
            if (tid < 16) {
                float s = outred[tid] + outred[16 + tid] + outred[32 + tid] + outred[48 + tid];
                out[(grp * 16 + tid) * (T_ * O_) + t * O_ + ntw] = s;
            }
        }

        // acquire edge: wait for all 16 WGs of the group (relaxed poll), then
        // load r_{t+1} fragments as coherent (sc1) u64 atomic loads — they
        // bypass stale L1/L2, so no acquire fence is needed.
        if (tid == 0) {
            const unsigned int tgt = 16u * (unsigned)(t + 1);
            while (__hip_atomic_load(myc, __ATOMIC_RELAXED, __HIP_MEMORY_SCOPE_AGENT) < tgt) { }
        }
        __syncthreads();

        {
            u16* rbl = g_rbuf + ((t + 1) & 1) * (B_ * H_) + (grp * 16 + lm) * H_ + kb;
#pragma unroll
            for (int kf = 0; kf < 8; ++kf) {
                unsigned long long* p = (unsigned long long*)(rbl + kf * 32 + 8 * lk);
                unsigned long long d0 = __hip_atomic_load(p + 0, __ATOMIC_RELAXED,
                                                          __HIP_MEMORY_SCOPE_AGENT);
                unsigned long long d1 = __hip_atomic_load(p + 1, __ATOMIC_RELAXED,
                                                          __HIP_MEMORY_SCOPE_AGENT);
                union { unsigned long long q[2]; short8 s; } cv;
                cv.q[0] = d0; cv.q[1] = d1;
                Af[kf] = cv.s;
            }
        }
    }

    // output row T-1 from r_{T-1}
    if (ntw < O_) {
        float po = 0.0f;
#pragma unroll
        for (int kf = 0; kf < 8; ++kf) {
            const short8 a = Af[kf];
#pragma unroll
            for (int i = 0; i < 8; ++i)
                po = fmaf(bf2f((u16)a[i]), wo[kf * 8 + i], po);
        }
        po += __shfl_xor(po, 16, 64);
        po += __shfl_xor(po, 32, 64);
        if (l < 16) outred[w * 16 + l] = po;
        __syncthreads();
        if (tid < 16) {
            float s = outred[tid] + outred[16 + tid] + outred[32 + tid] + outred[48 + tid];
            out[(grp * 16 + tid) * (T_ * O_) + (T_ - 1) * O_ + ntw] = s;
        }
    }
}

extern "C" void kernel_launch(void* const* d_in, const int* in_sizes, int n_in,
                              void* d_out, int out_size, void* d_ws, size_t ws_size,
                              hipStream_t stream) {
    (void)in_sizes; (void)n_in; (void)out_size; (void)d_ws; (void)ws_size;
    const float* x     = (const float*)d_in[0];
    const float* noise = (const float*)d_in[1];
    const float* wi    = (const float*)d_in[2];
    const float* wrec  = (const float*)d_in[3];
    const float* wout  = (const float*)d_in[4];
    const float* bb    = (const float*)d_in[5];
    const float* gg    = (const float*)d_in[6];
    const float* h0    = (const float*)d_in[7];
    // d_in[8] = refEI: derived analytically (ei[k] = k<819 ? 1 : -1), not needed
    const float* mwrec = (const float*)d_in[9];
    float* out = (float*)d_out;

    rnn_init<<<dim3(1), dim3(256), 0, stream>>>();
    rnn_persist<<<dim3(256), dim3(256), 0, stream>>>(
        x, noise, wi, wrec, wout, bb, gg, h0, mwrec, out);
}